// Round 13
// baseline (224.038 us; speedup 1.0000x reference)
//
#include <hip/hip_runtime.h>
#include <stdint.h>
#include <math.h>

// Problem shape (fixed by reference): xs [B,T,N,D] fp32, A [1,N,N] int32
#define BB 4
#define TT 32
#define NN 128
#define DD 32
#define NPB 16                       // nodes per block (16 nodes x 32 d = 512 threads)
#define TPB (NPB * DD)               // 512 threads
#define NBLK (BB * TT * (NN / NPB))  // 1024 blocks = exactly 4 per CU
#define CAP 16                       // band capacity; selected-bin overflow -> exact fallback
#define NK (CAP + 2)                 // 16 spatial slots + 2 temporal slots

// Arithmetic 8-bin partition of the value axis. ANY monotone non-decreasing
// bin function gives exact rank selection (equal values -> equal bins, so
// bins partition the multiset in value order). Median of ~66 N(0,1) lands in
// a bin with count <= CAP except ~1e-5/lane -> fallback is exact anyway.
__device__ __forceinline__ int bin8(float x) {
    int i = (int)fmaf(x, 5.0f, 4.0f);   // trunc; monotone non-decreasing
    i = i < 0 ? 0 : i;
    return i > 7 ? 7 : i;
}

// R13: code-size / I$ test + cleanup. Dispatch is 58us with only 19us/SIMD
// of VALU issue, HBM 0.8%, conflicts nil -- 2/3 of cycles stall with no
// throughput resource saturated. Last untested theory: instruction-fetch
// pressure from the huge body (two fully-unrolled cold fallback passes).
// (1) Fallback -> ONE compact __noinline__ cold function doing exact
//     multiset selection at rank rp WITHIN THE BAND (the rank-r median
//     provably lies in selbin, so band-restricted selection is exact).
// (2) sbin/snbr/sdeg deleted: bitplane build reads sval f32 directly
//     (bank == dd, 2-way = free), dg = popcll(mask), fallback uses the
//     band mask. LDS 27.1 -> 20.7KB, staging loses the bin-pack step.
// If I$ was the stall: 58 -> 42-50us. If flat: remaining wall is the
// dependency-latency floor.
__device__ __attribute__((noinline))
float fb_band_median(const float* sval, int d,
                     unsigned long long b0, unsigned long long b1,
                     bool tb0, bool tb1, float e0, float e1, uint32_t rp) {
    // exact lower-median (rank rp) over the band multiset:
    // spatial members = set bits of b0|b1, temporal members via tb0/tb1.
    unsigned long long c0 = b0, c1 = b1;
    bool u0 = tb0, u1 = tb1;
    for (;;) {
        float vi;
        if (c0 | c1) {
            const bool lo = (c0 != 0ull);
            unsigned long long mm_ = lo ? c0 : c1;
            const int ff = __ffsll(mm_) - 1;
            const int id = lo ? ff : 64 + ff;
            vi = sval[id * DD + d];
            mm_ &= (mm_ - 1ull);
            if (lo) c0 = mm_; else c1 = mm_;
        } else if (u0) { vi = e0; u0 = false; }
        else if (u1)   { vi = e1; u1 = false; }
        else break;  // unreachable: some candidate always matches
        uint32_t lt = 0, le = 0;
        unsigned long long m0 = b0, m1 = b1;
        while (m0 | m1) {
            const bool lo = (m0 != 0ull);
            unsigned long long mm_ = lo ? m0 : m1;
            const int ff = __ffsll(mm_) - 1;
            const int id = lo ? ff : 64 + ff;
            const float x = sval[id * DD + d];
            lt += (x < vi) ? 1u : 0u;
            le += (x <= vi) ? 1u : 0u;
            mm_ &= (mm_ - 1ull);
            if (lo) m0 = mm_; else m1 = mm_;
        }
        if (tb0) { lt += (e0 < vi) ? 1u : 0u; le += (e0 <= vi) ? 1u : 0u; }
        if (tb1) { lt += (e1 < vi) ? 1u : 0u; le += (e1 <= vi) ? 1u : 0u; }
        if (lt <= rp && rp < le) return vi;
    }
    return 0.0f;
}

__global__ __launch_bounds__(TPB) void median_kernel(const float* __restrict__ xs,
                                                     const int* __restrict__ A,
                                                     float* __restrict__ out) {
    __shared__ __align__(16) float sval[NN * DD];       // 16 KB: current frame [n][d]
    __shared__ __align__(16) uint32_t sbit[8 * DD * 4]; // 4 KB: bitplanes [bin][d][n/32]
    __shared__ __align__(16) uint32_t smask[NPB][4];    // 256 B: adjacency masks

    const int tid = threadIdx.x;
    // Bijective XCD swizzle (NBLK % 8 == 0): each XCD gets a contiguous chunk
    // of 128 logical blocks = 16 whole frames -> frame re-reads are L2-local.
    const int bid = blockIdx.x;
    const int g = ((bid & 7) << 7) | (bid >> 3);
    const int ng = g & (NN / NPB - 1);       // % 8
    const int t  = (g >> 3) & (TT - 1);      // /8 % 32
    const int b  = g >> 8;                   // /256
    const int n0 = ng * NPB;

    const int d = tid & (DD - 1);
    const int nl = tid >> 5;  // local node 0..15
    const int n = n0 + nl;
    const int pv = (t > 0) ? 1 : 0;        // wave-uniform
    const int nv = (t < TT - 1) ? 1 : 0;   // wave-uniform
    const int ne = pv + nv;

    // temporal candidates as floats (coalesced; issued before the barrier)
    float exv0 = 0.0f, exv1 = 0.0f;
    if (pv) exv0 = xs[(((size_t)(b * TT + t - 1) * NN) + n) * DD + d];
    if (nv) {
        float v = xs[(((size_t)(b * TT + t + 1) * NN) + n) * DD + d];
        if (pv) exv1 = v; else exv0 = v;
    }

    // stage current frame (float4 coalesced)
    const float4* src4 = (const float4*)(xs + ((size_t)(b * TT + t) * NN) * DD);
    #pragma unroll
    for (int s = 0; s < 2; ++s) {
        int i4 = tid + (s << 9);
        ((float4*)sval)[i4] = src4[i4];
    }

    // ---- fused adjacency build: wave wid ballots rows 2*wid, 2*wid+1 of A
    // (+ implicit self loop) into raw mask words. A is 64KB, L2-resident.
    {
        const int lane = tid & 63;
        const int wid = tid >> 6;  // 0..7
        #pragma unroll
        for (int h = 0; h < 2; ++h) {
            const int rr = wid * 2 + h;          // local row 0..15
            const int nrow = n0 + rr;            // global node id
            const int* arow = A + nrow * NN;
            const bool b0 = (arow[lane] != 0) || (lane == nrow);
            const bool b1 = (arow[lane + 64] != 0) || (lane + 64 == nrow);
            const unsigned long long m0 = __ballot(b0);
            const unsigned long long m1 = __ballot(b1);
            if (lane == 0) {
                smask[rr][0] = (uint32_t)m0;
                smask[rr][1] = (uint32_t)(m0 >> 32);
                smask[rr][2] = (uint32_t)m1;
                smask[rr][3] = (uint32_t)(m1 >> 32);
            }
        }
    }
    __syncthreads();  // sval + smask ready

    // ---- ownership bitplane build: thread (rep, wo, dd) owns words
    // sbit[2rep..2rep+1][dd][wo]; 32 sval f32 reads (bank == dd, 2-way =
    // free), bin8 on the fly, all accumulation in registers, 2 stores. ----
    {
        const int rep = tid >> 7;        // 0..3 -> bins {2r, 2r+1}
        const int wo  = (tid >> 5) & 3;  // word 0..3 -> nodes [wo*32, wo*32+32)
        const int dd  = tid & 31;
        const int ba = rep * 2, bc = ba + 1;
        uint32_t lo = 0u, hi = 0u;
        #pragma unroll 8
        for (int q = 0; q < 32; ++q) {
            const int bv = bin8(sval[(wo * 32 + q) * DD + dd]);
            lo |= (bv == ba) ? (1u << q) : 0u;
            hi |= (bv == bc) ? (1u << q) : 0u;
        }
        sbit[ba * 128 + dd * 4 + wo] = lo;
        sbit[bc * 128 + dd * 4 + wo] = hi;
    }
    __syncthreads();  // bitplanes visible

    // adjacency mask for this node (16B, broadcast within the node-group)
    const uint4 am4 = *((const uint4*)smask[nl]);
    const unsigned long long am0 = (((unsigned long long)am4.y) << 32) | am4.x;
    const unsigned long long am1 = (((unsigned long long)am4.w) << 32) | am4.z;
    const int dg = __popcll(am0) + __popcll(am1);
    const int k = dg + ne;
    const uint32_t r = (uint32_t)((k - 1) >> 1);  // lower-median rank (0-based)
    const float INFV = __uint_as_float(0x7F800000u);
    const int be0 = bin8(exv0);
    const int be1 = bin8(exv1);

    // ---- A1: bitplane histogram -- 8 x (b128 read, AND, popcount) ----
    int hist[8];
    const uint4* sbit4 = (const uint4*)sbit;
    #pragma unroll
    for (int bb = 0; bb < 8; ++bb) {
        uint4 w = sbit4[bb * 32 + d];
        hist[bb] = __popc(w.x & am4.x) + __popc(w.y & am4.y)
                 + __popc(w.z & am4.z) + __popc(w.w & am4.w);
    }

    // ---- prefix over bins (temporal folded in); select bin containing r ----
    uint32_t cum = 0, lowcnt = 0, mexp = 0;
    int selbin = -1;
    #pragma unroll
    for (int bb = 0; bb < 8; ++bb) {
        uint32_t bc = (uint32_t)hist[bb] + ((ne >= 1 && be0 == bb) ? 1u : 0u)
                                         + ((ne == 2 && be1 == bb) ? 1u : 0u);
        uint32_t nc = cum + bc;
        if (selbin < 0 && r < nc) { selbin = bb; lowcnt = cum; mexp = bc; }
        cum = nc;
    }
    const bool fb = (mexp > CAP);   // band too big -> exact cold fallback
    const uint32_t rp = r - lowcnt; // rank within band
    const bool tb0 = (ne >= 1) && (be0 == selbin);  // temporal in band
    const bool tb1 = (ne == 2) && (be1 == selbin);

    // ---- A2: band mask (selbin always valid 0..7) + static ffs-walk ----
    const uint4 wsel = sbit4[selbin * 32 + d];
    unsigned long long bm0 = (((unsigned long long)(wsel.y & am4.y)) << 32) | (wsel.x & am4.x);
    unsigned long long bm1 = (((unsigned long long)(wsel.w & am4.w)) << 32) | (wsel.z & am4.z);
    const int mc_sp = fb ? 0 : (__popcll(bm0) + __popcll(bm1));
    {
        unsigned long long c0 = bm0, c1 = bm1;
        int ids[CAP];
        #pragma unroll
        for (int u = 0; u < CAP; ++u) {
            const bool lo = (c0 != 0ull);
            const unsigned long long mm_ = lo ? c0 : c1;
            const int ff = __ffsll(mm_) - 1;  // -1 when empty
            ids[u] = (lo ? ff : 64 + ff) & 127;  // in-bounds always
            const unsigned long long cl = mm_ & (mm_ - 1ull);
            c0 = lo ? cl : c0;
            c1 = lo ? c1 : cl;
        }

        // ---- gather band values: 16 independent sval reads, bank == d for
        // ANY id (addr = id*32+d) -> conflict-free by construction ----
        float ki[NK];
        #pragma unroll
        for (int u = 0; u < CAP; ++u)
            ki[u] = (u < mc_sp) ? sval[ids[u] * DD + d] : INFV;
        const bool t0 = tb0 && !fb;
        const bool t1 = tb1 && !fb;
        ki[CAP]     = t0 ? exv0 : INFV;
        ki[CAP + 1] = t1 ? exv1 : INFV;

        // ---- rank within band: antisymmetric triangular compares (exact).
        // One compare per unordered pair ranks by total order (value, index):
        // ranks are a unique permutation; rank-rp value == multiset lower
        // median. INF padding ranks above all finite; mexp >= rp+1 => the
        // rank-rp slot is valid. No dup pass needed (ties break by index).
        uint32_t cn[NK];
        #pragma unroll
        for (int u = 0; u < NK; ++u) cn[u] = 0;
        #pragma unroll
        for (int u = 0; u < NK; ++u) {
            #pragma unroll
            for (int v = u + 1; v < NK; ++v) {
                const bool lt = ki[v] < ki[u];   // v strictly below u
                cn[u] += lt ? 1u : 0u;
                cn[v] += lt ? 0u : 1u;           // u at or below v (u < v)
            }
        }
        float result = 0.0f;
        #pragma unroll
        for (int u = 0; u < NK; ++u) {
            const bool valid = (u < CAP) ? (u < mc_sp) : ((u == CAP) ? t0 : t1);
            if (valid && cn[u] == rp) result = ki[u];  // unique match
        }

        // ---- cold exact fallback (band > CAP; ~1e-5 of lanes) ----
        if (fb) result = fb_band_median(sval, d, bm0, bm1, tb0, tb1, exv0, exv1, rp);

        out[(((size_t)(b * TT + t) * NN) + n) * DD + d] = result;
    }
}

extern "C" void kernel_launch(void* const* d_in, const int* in_sizes, int n_in,
                              void* d_out, int out_size, void* d_ws, size_t ws_size,
                              hipStream_t stream) {
    const float* xs = (const float*)d_in[0];
    const int* A = (const int*)d_in[1];
    float* out = (float*)d_out;
    (void)d_ws; (void)ws_size;  // no workspace: adjacency fused into the kernel

    median_kernel<<<NBLK, TPB, 0, stream>>>(xs, A, out);
}

// Round 15
// 112.251 us; speedup vs baseline: 1.9959x; 1.9959x over previous
//
#include <hip/hip_runtime.h>
#include <stdint.h>
#include <math.h>

// Problem shape (fixed by reference): xs [B,T,N,D] fp32, A [1,N,N] int32
#define BB 4
#define TT 32
#define NN 128
#define DD 32
#define NPB 16                       // nodes per block (16 nodes x 32 d = 512 threads)
#define TPB (NPB * DD)               // 512 threads
#define NBLK (BB * TT * (NN / NPB))  // 1024 blocks = exactly 4 per CU
#define CAP 16                       // band capacity; selected-bin overflow -> exact fallback
#define NK (CAP + 2)                 // 16 spatial slots + 2 temporal slots

// Arithmetic 8-bin partition of the value axis. ANY monotone non-decreasing
// bin function gives exact rank selection (equal values -> equal bins, so
// bins partition the multiset in value order). Median of ~66 N(0,1) lands in
// a bin with count <= CAP except ~1e-5/lane -> fallback is exact anyway.
__device__ __forceinline__ int bin8(float x) {
    int i = (int)fmaf(x, 5.0f, 4.0f);   // trunc; monotone non-decreasing
    i = i < 0 ? 0 : i;
    return i > 7 ? 7 : i;
}

// R15 == R14 resubmit (R14 bench was an infra failure, no data; R2/R8
// precedent: identical source passed on resubmit).
// R14 = R12 (certified 58.4us) + ONE kept change from R13: sbin deleted
// (bitplane build reads sval f32 directly, bin8 on the fly). R13's 199us
// was a STRAGGLER TAIL, not the main body: its compact __noinline__
// fallback was a serial dependent mask-walk (~100K cycles/fb-wave); the
// ~1e-5 band-overflow lanes extended the dispatch by ~145us (Occ 22->7%,
// VALUBusy 33->11% are dilution signatures). Lesson: cold paths must stay
// BOUNDED per wave -- the dispatch ends at the last straggler. R12's
// 8-wide-ILP fallback (counter-indexed reads, pipelined) is restored
// verbatim, along with snbr/sdeg.
__global__ __launch_bounds__(TPB) void median_kernel(const float* __restrict__ xs,
                                                     const int* __restrict__ A,
                                                     float* __restrict__ out) {
    __shared__ __align__(16) float sval[NN * DD];       // 16 KB: current frame [n][d]
    __shared__ __align__(16) uint32_t sbit[8 * DD * 4]; // 4 KB: bitplanes [bin][d][n/32]
    __shared__ uint32_t snbr_w[NPB * NN / 4];   // 2 KB: neighbor id lists (u8, fallback only)
    __shared__ __align__(16) uint32_t smask[NPB][4];    // 256 B: adjacency masks
    __shared__ int sdeg[NPB];

    const int tid = threadIdx.x;
    // Bijective XCD swizzle (NBLK % 8 == 0): each XCD gets a contiguous chunk
    // of 128 logical blocks = 16 whole frames -> frame re-reads are L2-local.
    const int bid = blockIdx.x;
    const int g = ((bid & 7) << 7) | (bid >> 3);
    const int ng = g & (NN / NPB - 1);       // % 8
    const int t  = (g >> 3) & (TT - 1);      // /8 % 32
    const int b  = g >> 8;                   // /256
    const int n0 = ng * NPB;

    const int d = tid & (DD - 1);
    const int nl = tid >> 5;  // local node 0..15
    const int n = n0 + nl;
    const int pv = (t > 0) ? 1 : 0;        // wave-uniform
    const int nv = (t < TT - 1) ? 1 : 0;   // wave-uniform
    const int ne = pv + nv;

    // temporal candidates as floats (coalesced; issued before the barrier)
    float exv0 = 0.0f, exv1 = 0.0f;
    if (pv) exv0 = xs[(((size_t)(b * TT + t - 1) * NN) + n) * DD + d];
    if (nv) {
        float v = xs[(((size_t)(b * TT + t + 1) * NN) + n) * DD + d];
        if (pv) exv1 = v; else exv0 = v;
    }

    // stage current frame (float4 coalesced; no bin pack -- sbin deleted)
    const float4* src4 = (const float4*)(xs + ((size_t)(b * TT + t) * NN) * DD);
    #pragma unroll
    for (int s = 0; s < 2; ++s) {
        int i4 = tid + (s << 9);
        ((float4*)sval)[i4] = src4[i4];
    }

    // ---- fused adjacency build: wave wid ballots rows 2*wid, 2*wid+1 of A
    // (+ implicit self loop) into compacted u8 lists AND raw mask words.
    {
        uint8_t* snbr = (uint8_t*)snbr_w;
        const int lane = tid & 63;
        const int wid = tid >> 6;  // 0..7
        const unsigned long long lmask = (1ULL << lane) - 1ULL;
        #pragma unroll
        for (int h = 0; h < 2; ++h) {
            const int rr = wid * 2 + h;          // local row 0..15
            const int nrow = n0 + rr;            // global node id
            const int* arow = A + nrow * NN;
            const bool b0 = (arow[lane] != 0) || (lane == nrow);
            const bool b1 = (arow[lane + 64] != 0) || (lane + 64 == nrow);
            const unsigned long long m0 = __ballot(b0);
            const unsigned long long m1 = __ballot(b1);
            const int c0 = __popcll(m0);
            if (b0) snbr[rr * NN + __popcll(m0 & lmask)] = (uint8_t)lane;
            if (b1) snbr[rr * NN + c0 + __popcll(m1 & lmask)] = (uint8_t)(lane + 64);
            if (lane == 0) {
                sdeg[rr] = c0 + __popcll(m1);
                smask[rr][0] = (uint32_t)m0;
                smask[rr][1] = (uint32_t)(m0 >> 32);
                smask[rr][2] = (uint32_t)m1;
                smask[rr][3] = (uint32_t)(m1 >> 32);
            }
        }
    }
    __syncthreads();  // sval/snbr/smask ready

    // ---- ownership bitplane build: thread (rep, wo, dd) owns words
    // sbit[2rep..2rep+1][dd][wo]; 32 sval f32 reads (bank == dd, 2-way =
    // free), bin8 on the fly, accumulation in registers, 2 stores. ----
    {
        const int rep = tid >> 7;        // 0..3 -> bins {2r, 2r+1}
        const int wo  = (tid >> 5) & 3;  // word 0..3 -> nodes [wo*32, wo*32+32)
        const int dd  = tid & 31;
        const int ba = rep * 2, bc = ba + 1;
        uint32_t lo = 0u, hi = 0u;
        #pragma unroll 8
        for (int q = 0; q < 32; ++q) {
            const int bv = bin8(sval[(wo * 32 + q) * DD + dd]);
            lo |= (bv == ba) ? (1u << q) : 0u;
            hi |= (bv == bc) ? (1u << q) : 0u;
        }
        sbit[ba * 128 + dd * 4 + wo] = lo;
        sbit[bc * 128 + dd * 4 + wo] = hi;
    }
    __syncthreads();  // bitplanes visible

    const int dg = sdeg[nl];
    const int k = dg + ne;
    const uint32_t r = (uint32_t)((k - 1) >> 1);  // lower-median rank (0-based)
    const uint8_t* nb = (const uint8_t*)snbr_w + nl * NN;
    const float INFV = __uint_as_float(0x7F800000u);
    const int be0 = bin8(exv0);
    const int be1 = bin8(exv1);

    // ---- A1: bitplane histogram -- 8 x (b128 read, AND, popcount) ----
    const uint4 am4 = *((const uint4*)smask[nl]);  // broadcast within node-group
    int hist[8];
    const uint4* sbit4 = (const uint4*)sbit;
    #pragma unroll
    for (int bb = 0; bb < 8; ++bb) {
        uint4 w = sbit4[bb * 32 + d];
        hist[bb] = __popc(w.x & am4.x) + __popc(w.y & am4.y)
                 + __popc(w.z & am4.z) + __popc(w.w & am4.w);
    }

    // ---- prefix over bins (temporal folded in); select bin containing r ----
    uint32_t cum = 0, lowcnt = 0, mexp = 0;
    int selbin = -1;
    #pragma unroll
    for (int bb = 0; bb < 8; ++bb) {
        uint32_t bc = (uint32_t)hist[bb] + ((ne >= 1 && be0 == bb) ? 1u : 0u)
                                         + ((ne == 2 && be1 == bb) ? 1u : 0u);
        uint32_t nc = cum + bc;
        if (selbin < 0 && r < nc) { selbin = bb; lowcnt = cum; mexp = bc; }
        cum = nc;
    }
    const bool fb = (mexp > CAP);   // band too big -> exact fallback (~1e-5)
    const uint32_t rp = r - lowcnt; // rank within band

    // ---- A2: static ffs-walk of the band bitmask -> id register array ----
    const uint4 wsel = sbit4[selbin * 32 + d];   // selbin always in 0..7
    unsigned long long bm0 = (((unsigned long long)(wsel.y & am4.y)) << 32) | (wsel.x & am4.x);
    unsigned long long bm1 = (((unsigned long long)(wsel.w & am4.w)) << 32) | (wsel.z & am4.z);
    const int mc_sp = fb ? 0 : (__popcll(bm0) + __popcll(bm1));
    int ids[CAP];
    #pragma unroll
    for (int u = 0; u < CAP; ++u) {
        const bool lo = (bm0 != 0ull);
        const unsigned long long mm_ = lo ? bm0 : bm1;
        const int ff = __ffsll(mm_) - 1;  // -1 when empty
        ids[u] = (lo ? ff : 64 + ff) & 127;                   // in-bounds always
        const unsigned long long cl = mm_ & (mm_ - 1ull);
        bm0 = lo ? cl : bm0;
        bm1 = lo ? bm1 : cl;
    }

    // ---- gather band values: 16 independent sval reads, bank == d for ANY
    // id (addr = id*32+d) -> conflict-free by construction ----
    float ki[NK];
    #pragma unroll
    for (int u = 0; u < CAP; ++u)
        ki[u] = (u < mc_sp) ? sval[ids[u] * DD + d] : INFV;
    const bool t0 = (ne >= 1) && (be0 == selbin) && !fb;
    const bool t1 = (ne == 2) && (be1 == selbin) && !fb;
    ki[CAP]     = t0 ? exv0 : INFV;
    ki[CAP + 1] = t1 ? exv1 : INFV;

    // ---- rank within band: antisymmetric triangular compares (exact).
    // One compare per unordered pair ranks by total order (value, index):
    // ranks are a unique permutation; rank-rp value == multiset lower
    // median. INF padding ranks above all finite; mexp >= rp+1 => the
    // rank-rp slot is valid. No dup pass needed (ties break by index).
    uint32_t cn[NK];
    #pragma unroll
    for (int u = 0; u < NK; ++u) cn[u] = 0;
    #pragma unroll
    for (int u = 0; u < NK; ++u) {
        #pragma unroll
        for (int v = u + 1; v < NK; ++v) {
            const bool lt = ki[v] < ki[u];   // v strictly below u
            cn[u] += lt ? 1u : 0u;
            cn[v] += lt ? 0u : 1u;           // u at or below v (u < v)
        }
    }
    float result = 0.0f;
    #pragma unroll
    for (int u = 0; u < NK; ++u) {
        const bool valid = (u < CAP) ? (u < mc_sp) : ((u == CAP) ? t0 : t1);
        if (valid && cn[u] == rp) result = ki[u];  // unique match
    }

    // ---- full fallback (band > CAP; ~1e-5 of lanes): R12's BOUNDED
    // 8-wide-ILP exact scan over all k (counter-indexed reads pipeline;
    // serial mask-walk variants create 150us straggler tails -- R13). ----
    if (__ballot(fb)) {
        bool done = !fb;
        for (int i0 = 0; __ballot(!done && i0 < k); i0 += 8) {
            float k8[8]; uint32_t c8[8];
            #pragma unroll
            for (int u = 0; u < 8; ++u) {
                int i = i0 + u;
                float sv = sval[nb[i & 127] * DD + d];
                float ev = ((i - dg) == 0) ? exv0 : exv1;
                float v = (i < dg) ? sv : ev;
                k8[u] = (i < k) ? v : INFV;
                c8[u] = 0;
            }
            for (int j = 0; j < dg; ++j) {
                float xv = sval[nb[j] * DD + d];
                #pragma unroll
                for (int u = 0; u < 8; ++u) c8[u] += (xv < k8[u]);
            }
            if (ne >= 1) {
                #pragma unroll
                for (int u = 0; u < 8; ++u) c8[u] += (exv0 < k8[u]);
            }
            if (ne == 2) {
                #pragma unroll
                for (int u = 0; u < 8; ++u) c8[u] += (exv1 < k8[u]);
            }
            #pragma unroll
            for (int u = 0; u < 8; ++u) {
                if (!done && (i0 + u) < k && c8[u] == r) { result = k8[u]; done = true; }
            }
        }
        if (__ballot(!done)) {  // duplicates across rank: exact multiset selection
            for (int i0 = 0; __ballot(!done && i0 < k); i0 += 4) {
                float k4[4]; uint32_t lt4[4], le4[4];
                #pragma unroll
                for (int u = 0; u < 4; ++u) {
                    int i = i0 + u;
                    float sv = sval[nb[i & 127] * DD + d];
                    float ev = ((i - dg) == 0) ? exv0 : exv1;
                    float v = (i < dg) ? sv : ev;
                    k4[u] = (i < k) ? v : INFV;
                    lt4[u] = 0; le4[u] = 0;
                }
                for (int j = 0; j < dg; ++j) {
                    float xv = sval[nb[j] * DD + d];
                    #pragma unroll
                    for (int u = 0; u < 4; ++u) { lt4[u] += (xv < k4[u]); le4[u] += (xv <= k4[u]); }
                }
                if (ne >= 1) {
                    #pragma unroll
                    for (int u = 0; u < 4; ++u) { lt4[u] += (exv0 < k4[u]); le4[u] += (exv0 <= k4[u]); }
                }
                if (ne == 2) {
                    #pragma unroll
                    for (int u = 0; u < 4; ++u) { lt4[u] += (exv1 < k4[u]); le4[u] += (exv1 <= k4[u]); }
                }
                #pragma unroll
                for (int u = 0; u < 4; ++u) {
                    if (!done && (i0 + u) < k && lt4[u] <= r && r < le4[u]) {
                        result = k4[u]; done = true;
                    }
                }
            }
        }
    }

    out[(((size_t)(b * TT + t) * NN) + n) * DD + d] = result;
}

extern "C" void kernel_launch(void* const* d_in, const int* in_sizes, int n_in,
                              void* d_out, int out_size, void* d_ws, size_t ws_size,
                              hipStream_t stream) {
    const float* xs = (const float*)d_in[0];
    const int* A = (const int*)d_in[1];
    float* out = (float*)d_out;
    (void)d_ws; (void)ws_size;  // no workspace: adjacency fused into the kernel

    median_kernel<<<NBLK, TPB, 0, stream>>>(xs, A, out);
}

// Round 16
// 111.053 us; speedup vs baseline: 2.0174x; 1.0108x over previous
//
#include <hip/hip_runtime.h>
#include <stdint.h>
#include <math.h>

// Problem shape (fixed by reference): xs [B,T,N,D] fp32, A [1,N,N] int32
#define BB 4
#define TT 32
#define NN 128
#define DD 32
#define NPB 32                       // nodes per block (32 nodes x 32 d = 1024 threads)
#define TPB (NPB * DD)               // 1024 threads = 16 waves
#define NBLK (BB * TT * (NN / NPB))  // 512 blocks = 2 per CU
#define CAP 16                       // band capacity; selected-bin overflow -> exact fallback
#define NK (CAP + 2)                 // 16 spatial slots + 2 temporal slots

// Arithmetic 8-bin partition of the value axis. ANY monotone non-decreasing
// bin function gives exact rank selection (equal values -> equal bins, so
// bins partition the multiset in value order). Median of ~66 N(0,1) lands in
// a bin with count <= CAP except ~1e-5/lane -> fallback is exact anyway.
__device__ __forceinline__ int bin8(float x) {
    int i = (int)fmaf(x, 5.0f, 4.0f);   // trunc; monotone non-decreasing
    i = i < 0 ? 0 : i;
    return i > 7 ? 7 : i;
}

// R16: block-shape experiment on the certified R12 body. R15's A/B settled
// the build question (sbin indirection wins by 8us -- restored here). Its
// diagnostic gem: avg resident blocks/CU ~= 0.74-1.3 across ALL rounds
// (Occ x 32 / 8 waves), i.e. blocks effectively serialize per CU and wall
// ~= 4 x single-block time. Waves WITHIN a block always co-reside, so this
// round packs 16 waves into 1024-thread blocks (NPB=32, 512 blocks = 2/CU),
// still 1 output/thread (R6's regression was 2 outputs/thread -- different
// variable). Per-thread phases shrink: staging 1 float4, build 1 word.
// Pre-committed read: 38-48us => serialization model right; 55-65 flat =>
// blocks co-reside after all; >=70 => 16-wave barriers toxic, revert R12.
__global__ __launch_bounds__(TPB) void median_kernel(const float* __restrict__ xs,
                                                     const int* __restrict__ A,
                                                     float* __restrict__ out) {
    __shared__ __align__(16) float sval[NN * DD];       // 16 KB: current frame [n][d]
    __shared__ uint8_t sbin[NN * DD];                   // 4 KB: per-element bin (0..7)
    __shared__ __align__(16) uint32_t sbit[8 * DD * 4]; // 4 KB: bitplanes [bin][d][n/32]
    __shared__ uint32_t snbr_w[NPB * NN / 4];           // 4 KB: neighbor ids (fallback only)
    __shared__ __align__(16) uint32_t smask[NPB][4];    // 512 B: adjacency masks
    __shared__ int sdeg[NPB];

    const int tid = threadIdx.x;
    // Bijective XCD swizzle (NBLK % 8 == 0): each XCD gets a contiguous chunk
    // of 64 logical blocks -> frame re-reads are L2-local.
    const int bid = blockIdx.x;
    const int g = ((bid & 7) << 6) | (bid >> 3);
    const int ng = g & (NN / NPB - 1);       // % 4
    const int t  = (g >> 2) & (TT - 1);      // /4 % 32
    const int b  = g >> 7;                   // /128
    const int n0 = ng * NPB;

    const int d = tid & (DD - 1);
    const int nl = tid >> 5;  // local node 0..31
    const int n = n0 + nl;
    const int pv = (t > 0) ? 1 : 0;        // wave-uniform
    const int nv = (t < TT - 1) ? 1 : 0;   // wave-uniform
    const int ne = pv + nv;

    // temporal candidates as floats (coalesced; issued before the barrier)
    float exv0 = 0.0f, exv1 = 0.0f;
    if (pv) exv0 = xs[(((size_t)(b * TT + t - 1) * NN) + n) * DD + d];
    if (nv) {
        float v = xs[(((size_t)(b * TT + t + 1) * NN) + n) * DD + d];
        if (pv) exv1 = v; else exv0 = v;
    }

    // stage current frame (float4 coalesced) + per-element bins (u32-packed):
    // exactly one float4 + one sbin word per thread
    {
        const float4* src4 = (const float4*)(xs + ((size_t)(b * TT + t) * NN) * DD);
        float4 f = src4[tid];
        ((float4*)sval)[tid] = f;
        uint32_t pk = (uint32_t)bin8(f.x) | ((uint32_t)bin8(f.y) << 8)
                    | ((uint32_t)bin8(f.z) << 16) | ((uint32_t)bin8(f.w) << 24);
        ((uint32_t*)sbin)[tid] = pk;
    }

    // ---- fused adjacency build: wave wid ballots rows 2*wid, 2*wid+1 of A
    // (+ implicit self loop) into compacted u8 lists AND raw mask words.
    {
        uint8_t* snbr = (uint8_t*)snbr_w;
        const int lane = tid & 63;
        const int wid = tid >> 6;  // 0..15
        const unsigned long long lmask = (1ULL << lane) - 1ULL;
        #pragma unroll
        for (int h = 0; h < 2; ++h) {
            const int rr = wid * 2 + h;          // local row 0..31
            const int nrow = n0 + rr;            // global node id
            const int* arow = A + nrow * NN;
            const bool b0 = (arow[lane] != 0) || (lane == nrow);
            const bool b1 = (arow[lane + 64] != 0) || (lane + 64 == nrow);
            const unsigned long long m0 = __ballot(b0);
            const unsigned long long m1 = __ballot(b1);
            const int c0 = __popcll(m0);
            if (b0) snbr[rr * NN + __popcll(m0 & lmask)] = (uint8_t)lane;
            if (b1) snbr[rr * NN + c0 + __popcll(m1 & lmask)] = (uint8_t)(lane + 64);
            if (lane == 0) {
                sdeg[rr] = c0 + __popcll(m1);
                smask[rr][0] = (uint32_t)m0;
                smask[rr][1] = (uint32_t)(m0 >> 32);
                smask[rr][2] = (uint32_t)m1;
                smask[rr][3] = (uint32_t)(m1 >> 32);
            }
        }
    }
    __syncthreads();  // sval/sbin/snbr/smask ready

    // ---- ownership bitplane build: thread (bin, wo, dd) owns ONE word;
    // 32 sbin byte reads (same-word broadcast within 4-lane groups -> ~free),
    // accumulation in a register, 1 store. ----
    {
        const int bno = tid >> 7;        // 0..7: the bin this thread owns
        const int wo  = (tid >> 5) & 3;  // word 0..3 -> nodes [wo*32, wo*32+32)
        const int dd  = tid & 31;
        uint32_t w = 0u;
        #pragma unroll 8
        for (int q = 0; q < 32; ++q) {
            const int bv = (int)sbin[(wo * 32 + q) * DD + dd];
            w |= (bv == bno) ? (1u << q) : 0u;
        }
        sbit[bno * 128 + dd * 4 + wo] = w;
    }
    __syncthreads();  // bitplanes visible

    const int dg = sdeg[nl];
    const int k = dg + ne;
    const uint32_t r = (uint32_t)((k - 1) >> 1);  // lower-median rank (0-based)
    const uint8_t* nb = (const uint8_t*)snbr_w + nl * NN;
    const float INFV = __uint_as_float(0x7F800000u);
    const int be0 = bin8(exv0);
    const int be1 = bin8(exv1);

    // ---- A1: bitplane histogram -- 8 x (b128 read, AND, popcount) ----
    const uint4 am4 = *((const uint4*)smask[nl]);  // broadcast within node-group
    int hist[8];
    const uint4* sbit4 = (const uint4*)sbit;
    #pragma unroll
    for (int bb = 0; bb < 8; ++bb) {
        uint4 w = sbit4[bb * 32 + d];
        hist[bb] = __popc(w.x & am4.x) + __popc(w.y & am4.y)
                 + __popc(w.z & am4.z) + __popc(w.w & am4.w);
    }

    // ---- prefix over bins (temporal folded in); select bin containing r ----
    uint32_t cum = 0, lowcnt = 0, mexp = 0;
    int selbin = -1;
    #pragma unroll
    for (int bb = 0; bb < 8; ++bb) {
        uint32_t bc = (uint32_t)hist[bb] + ((ne >= 1 && be0 == bb) ? 1u : 0u)
                                         + ((ne == 2 && be1 == bb) ? 1u : 0u);
        uint32_t nc = cum + bc;
        if (selbin < 0 && r < nc) { selbin = bb; lowcnt = cum; mexp = bc; }
        cum = nc;
    }
    const bool fb = (mexp > CAP);   // band too big -> exact fallback (~1e-5)
    const uint32_t rp = r - lowcnt; // rank within band

    // ---- A2: static ffs-walk of the band bitmask -> id register array ----
    const uint4 wsel = sbit4[selbin * 32 + d];   // selbin always in 0..7
    unsigned long long bm0 = (((unsigned long long)(wsel.y & am4.y)) << 32) | (wsel.x & am4.x);
    unsigned long long bm1 = (((unsigned long long)(wsel.w & am4.w)) << 32) | (wsel.z & am4.z);
    const int mc_sp = fb ? 0 : (__popcll(bm0) + __popcll(bm1));
    int ids[CAP];
    #pragma unroll
    for (int u = 0; u < CAP; ++u) {
        const bool lo = (bm0 != 0ull);
        const unsigned long long mm_ = lo ? bm0 : bm1;
        const int ff = __ffsll(mm_) - 1;  // -1 when empty
        ids[u] = (lo ? ff : 64 + ff) & 127;                   // in-bounds always
        const unsigned long long cl = mm_ & (mm_ - 1ull);
        bm0 = lo ? cl : bm0;
        bm1 = lo ? bm1 : cl;
    }

    // ---- gather band values: 16 independent sval reads, bank == d for ANY
    // id (addr = id*32+d) -> conflict-free by construction ----
    float ki[NK];
    #pragma unroll
    for (int u = 0; u < CAP; ++u)
        ki[u] = (u < mc_sp) ? sval[ids[u] * DD + d] : INFV;
    const bool t0 = (ne >= 1) && (be0 == selbin) && !fb;
    const bool t1 = (ne == 2) && (be1 == selbin) && !fb;
    ki[CAP]     = t0 ? exv0 : INFV;
    ki[CAP + 1] = t1 ? exv1 : INFV;

    // ---- rank within band: antisymmetric triangular compares (exact).
    // One compare per unordered pair ranks by total order (value, index):
    // ranks are a unique permutation; rank-rp value == multiset lower
    // median. INF padding ranks above all finite; mexp >= rp+1 => the
    // rank-rp slot is valid. No dup pass needed (ties break by index).
    uint32_t cn[NK];
    #pragma unroll
    for (int u = 0; u < NK; ++u) cn[u] = 0;
    #pragma unroll
    for (int u = 0; u < NK; ++u) {
        #pragma unroll
        for (int v = u + 1; v < NK; ++v) {
            const bool lt = ki[v] < ki[u];   // v strictly below u
            cn[u] += lt ? 1u : 0u;
            cn[v] += lt ? 0u : 1u;           // u at or below v (u < v)
        }
    }
    float result = 0.0f;
    #pragma unroll
    for (int u = 0; u < NK; ++u) {
        const bool valid = (u < CAP) ? (u < mc_sp) : ((u == CAP) ? t0 : t1);
        if (valid && cn[u] == rp) result = ki[u];  // unique match
    }

    // ---- full fallback (band > CAP; ~1e-5 of lanes): BOUNDED 8-wide-ILP
    // exact scan over all k (serial mask-walks create straggler tails, R13) ----
    if (__ballot(fb)) {
        bool done = !fb;
        for (int i0 = 0; __ballot(!done && i0 < k); i0 += 8) {
            float k8[8]; uint32_t c8[8];
            #pragma unroll
            for (int u = 0; u < 8; ++u) {
                int i = i0 + u;
                float sv = sval[nb[i & 127] * DD + d];
                float ev = ((i - dg) == 0) ? exv0 : exv1;
                float v = (i < dg) ? sv : ev;
                k8[u] = (i < k) ? v : INFV;
                c8[u] = 0;
            }
            for (int j = 0; j < dg; ++j) {
                float xv = sval[nb[j] * DD + d];
                #pragma unroll
                for (int u = 0; u < 8; ++u) c8[u] += (xv < k8[u]);
            }
            if (ne >= 1) {
                #pragma unroll
                for (int u = 0; u < 8; ++u) c8[u] += (exv0 < k8[u]);
            }
            if (ne == 2) {
                #pragma unroll
                for (int u = 0; u < 8; ++u) c8[u] += (exv1 < k8[u]);
            }
            #pragma unroll
            for (int u = 0; u < 8; ++u) {
                if (!done && (i0 + u) < k && c8[u] == r) { result = k8[u]; done = true; }
            }
        }
        if (__ballot(!done)) {  // duplicates across rank: exact multiset selection
            for (int i0 = 0; __ballot(!done && i0 < k); i0 += 4) {
                float k4[4]; uint32_t lt4[4], le4[4];
                #pragma unroll
                for (int u = 0; u < 4; ++u) {
                    int i = i0 + u;
                    float sv = sval[nb[i & 127] * DD + d];
                    float ev = ((i - dg) == 0) ? exv0 : exv1;
                    float v = (i < dg) ? sv : ev;
                    k4[u] = (i < k) ? v : INFV;
                    lt4[u] = 0; le4[u] = 0;
                }
                for (int j = 0; j < dg; ++j) {
                    float xv = sval[nb[j] * DD + d];
                    #pragma unroll
                    for (int u = 0; u < 4; ++u) { lt4[u] += (xv < k4[u]); le4[u] += (xv <= k4[u]); }
                }
                if (ne >= 1) {
                    #pragma unroll
                    for (int u = 0; u < 4; ++u) { lt4[u] += (exv0 < k4[u]); le4[u] += (exv0 <= k4[u]); }
                }
                if (ne == 2) {
                    #pragma unroll
                    for (int u = 0; u < 4; ++u) { lt4[u] += (exv1 < k4[u]); le4[u] += (exv1 <= k4[u]); }
                }
                #pragma unroll
                for (int u = 0; u < 4; ++u) {
                    if (!done && (i0 + u) < k && lt4[u] <= r && r < le4[u]) {
                        result = k4[u]; done = true;
                    }
                }
            }
        }
    }

    out[(((size_t)(b * TT + t) * NN) + n) * DD + d] = result;
}

extern "C" void kernel_launch(void* const* d_in, const int* in_sizes, int n_in,
                              void* d_out, int out_size, void* d_ws, size_t ws_size,
                              hipStream_t stream) {
    const float* xs = (const float*)d_in[0];
    const int* A = (const int*)d_in[1];
    float* out = (float*)d_out;
    (void)d_ws; (void)ws_size;  // no workspace: adjacency fused into the kernel

    median_kernel<<<NBLK, TPB, 0, stream>>>(xs, A, out);
}

// Round 17
// 106.281 us; speedup vs baseline: 2.1080x; 1.0449x over previous
//
#include <hip/hip_runtime.h>
#include <stdint.h>
#include <math.h>

// Problem shape (fixed by reference): xs [B,T,N,D] fp32, A [1,N,N] int32
#define BB 4
#define TT 32
#define NN 128
#define DD 32
#define NPB 16                       // nodes per block (16 nodes x 32 d = 512 threads)
#define TPB (NPB * DD)               // 512 threads
#define NBLK (BB * TT * (NN / NPB))  // 1024 blocks = exactly 4 per CU
#define CAP 16                       // band capacity; selected-bin overflow -> exact fallback
#define NK (CAP + 2)                 // 16 spatial slots + 2 temporal slots

// Arithmetic 8-bin partition of the value axis. ANY monotone non-decreasing
// bin function gives exact rank selection (equal values -> equal bins, so
// bins partition the multiset in value order). Median of ~66 N(0,1) lands in
// a bin with count <= CAP except ~1e-5/lane -> fallback is exact anyway.
__device__ __forceinline__ int bin8(float x) {
    int i = (int)fmaf(x, 5.0f, 4.0f);   // trunc; monotone non-decreasing
    i = i < 0 ? 0 : i;
    return i > 7 ? 7 : i;
}

// R17 = R12 (certified 58.4us; R15/R16 shape experiments flat, reverted)
// with the triangular ranking (153 pairs x ~3 ops + validity logic, the
// largest VALU block) replaced by a Batcher odd-even SORTING NETWORK over
// the 18 band slots (~82 CE x min/max) + constant-index select of
// sorted[rp]. INF padding sorts high and valid-count = mexp > rp, so
// sorted[rp] is exactly the multiset lower median -- cn[], validity
// predicates, and unique-match logic all deleted. All network indices are
// compile-time (4-level unroll, constant bounds) so ki[] stays in VGPRs.
// NOTE (R16 lesson): gfx950 OccupancyPercent is a gfx94x-formula fallback
// and reads ~20% regardless of static geometry -- do not model from it.
__global__ __launch_bounds__(TPB) void median_kernel(const float* __restrict__ xs,
                                                     const int* __restrict__ A,
                                                     float* __restrict__ out) {
    __shared__ __align__(16) float sval[NN * DD];       // 16 KB: current frame [n][d]
    __shared__ uint8_t sbin[NN * DD];                   // 4 KB: per-element bin (0..7)
    __shared__ __align__(16) uint32_t sbit[8 * DD * 4]; // 4 KB: bitplanes [bin][d][n/32]
    __shared__ uint32_t snbr_w[NPB * NN / 4];   // 2 KB: neighbor id lists (u8, fallback only)
    __shared__ __align__(16) uint32_t smask[NPB][4];    // 256 B: adjacency masks
    __shared__ int sdeg[NPB];

    const int tid = threadIdx.x;
    // Bijective XCD swizzle (NBLK % 8 == 0): each XCD gets a contiguous chunk
    // of 128 logical blocks = 16 whole frames -> frame re-reads are L2-local.
    const int bid = blockIdx.x;
    const int g = ((bid & 7) << 7) | (bid >> 3);
    const int ng = g & (NN / NPB - 1);       // % 8
    const int t  = (g >> 3) & (TT - 1);      // /8 % 32
    const int b  = g >> 8;                   // /256
    const int n0 = ng * NPB;

    const int d = tid & (DD - 1);
    const int nl = tid >> 5;  // local node 0..15
    const int n = n0 + nl;
    const int pv = (t > 0) ? 1 : 0;        // wave-uniform
    const int nv = (t < TT - 1) ? 1 : 0;   // wave-uniform
    const int ne = pv + nv;

    // temporal candidates as floats (coalesced; issued before the barrier)
    float exv0 = 0.0f, exv1 = 0.0f;
    if (pv) exv0 = xs[(((size_t)(b * TT + t - 1) * NN) + n) * DD + d];
    if (nv) {
        float v = xs[(((size_t)(b * TT + t + 1) * NN) + n) * DD + d];
        if (pv) exv1 = v; else exv0 = v;
    }

    // stage current frame (float4 coalesced) + per-element bins (u32-packed)
    const float4* src4 = (const float4*)(xs + ((size_t)(b * TT + t) * NN) * DD);
    #pragma unroll
    for (int s = 0; s < 2; ++s) {
        int i4 = tid + (s << 9);
        float4 f = src4[i4];
        ((float4*)sval)[i4] = f;
        uint32_t pk = (uint32_t)bin8(f.x) | ((uint32_t)bin8(f.y) << 8)
                    | ((uint32_t)bin8(f.z) << 16) | ((uint32_t)bin8(f.w) << 24);
        ((uint32_t*)sbin)[i4] = pk;
    }

    // ---- fused adjacency build: wave wid ballots rows 2*wid, 2*wid+1 of A
    // (+ implicit self loop) into compacted u8 lists AND raw mask words.
    {
        uint8_t* snbr = (uint8_t*)snbr_w;
        const int lane = tid & 63;
        const int wid = tid >> 6;  // 0..7
        const unsigned long long lmask = (1ULL << lane) - 1ULL;
        #pragma unroll
        for (int h = 0; h < 2; ++h) {
            const int rr = wid * 2 + h;          // local row 0..15
            const int nrow = n0 + rr;            // global node id
            const int* arow = A + nrow * NN;
            const bool b0 = (arow[lane] != 0) || (lane == nrow);
            const bool b1 = (arow[lane + 64] != 0) || (lane + 64 == nrow);
            const unsigned long long m0 = __ballot(b0);
            const unsigned long long m1 = __ballot(b1);
            const int c0 = __popcll(m0);
            if (b0) snbr[rr * NN + __popcll(m0 & lmask)] = (uint8_t)lane;
            if (b1) snbr[rr * NN + c0 + __popcll(m1 & lmask)] = (uint8_t)(lane + 64);
            if (lane == 0) {
                sdeg[rr] = c0 + __popcll(m1);
                smask[rr][0] = (uint32_t)m0;
                smask[rr][1] = (uint32_t)(m0 >> 32);
                smask[rr][2] = (uint32_t)m1;
                smask[rr][3] = (uint32_t)(m1 >> 32);
            }
        }
    }
    __syncthreads();  // sval/sbin/snbr/smask ready

    // ---- ownership bitplane build (sbin indirection: R15 A/B showed it
    // beats direct-f32 by 8us): thread (rep, wo, dd) owns 2 words; 32 sbin
    // byte reads (same-word broadcast -> ~free), regs, 2 stores. ----
    {
        const int rep = tid >> 7;        // 0..3 -> bins {2r, 2r+1}
        const int wo  = (tid >> 5) & 3;  // word 0..3 -> nodes [wo*32, wo*32+32)
        const int dd  = tid & 31;
        const int ba = rep * 2, bc = ba + 1;
        uint32_t lo = 0u, hi = 0u;
        #pragma unroll 8
        for (int q = 0; q < 32; ++q) {
            const int bv = (int)sbin[(wo * 32 + q) * DD + dd];
            lo |= (bv == ba) ? (1u << q) : 0u;
            hi |= (bv == bc) ? (1u << q) : 0u;
        }
        sbit[ba * 128 + dd * 4 + wo] = lo;
        sbit[bc * 128 + dd * 4 + wo] = hi;
    }
    __syncthreads();  // bitplanes visible

    const int dg = sdeg[nl];
    const int k = dg + ne;
    const uint32_t r = (uint32_t)((k - 1) >> 1);  // lower-median rank (0-based)
    const uint8_t* nb = (const uint8_t*)snbr_w + nl * NN;
    const float INFV = __uint_as_float(0x7F800000u);
    const int be0 = bin8(exv0);
    const int be1 = bin8(exv1);

    // ---- A1: bitplane histogram -- 8 x (b128 read, AND, popcount) ----
    const uint4 am4 = *((const uint4*)smask[nl]);  // broadcast within node-group
    int hist[8];
    const uint4* sbit4 = (const uint4*)sbit;
    #pragma unroll
    for (int bb = 0; bb < 8; ++bb) {
        uint4 w = sbit4[bb * 32 + d];
        hist[bb] = __popc(w.x & am4.x) + __popc(w.y & am4.y)
                 + __popc(w.z & am4.z) + __popc(w.w & am4.w);
    }

    // ---- prefix over bins (temporal folded in); select bin containing r ----
    uint32_t cum = 0, lowcnt = 0, mexp = 0;
    int selbin = -1;
    #pragma unroll
    for (int bb = 0; bb < 8; ++bb) {
        uint32_t bc = (uint32_t)hist[bb] + ((ne >= 1 && be0 == bb) ? 1u : 0u)
                                         + ((ne == 2 && be1 == bb) ? 1u : 0u);
        uint32_t nc = cum + bc;
        if (selbin < 0 && r < nc) { selbin = bb; lowcnt = cum; mexp = bc; }
        cum = nc;
    }
    const bool fb = (mexp > CAP);   // band too big -> exact fallback (~1e-5)
    const uint32_t rp = r - lowcnt; // rank within band

    // ---- A2: static ffs-walk of the band bitmask -> id register array ----
    const uint4 wsel = sbit4[selbin * 32 + d];   // selbin always in 0..7
    unsigned long long bm0 = (((unsigned long long)(wsel.y & am4.y)) << 32) | (wsel.x & am4.x);
    unsigned long long bm1 = (((unsigned long long)(wsel.w & am4.w)) << 32) | (wsel.z & am4.z);
    const int mc_sp = fb ? 0 : (__popcll(bm0) + __popcll(bm1));
    int ids[CAP];
    #pragma unroll
    for (int u = 0; u < CAP; ++u) {
        const bool lo = (bm0 != 0ull);
        const unsigned long long mm_ = lo ? bm0 : bm1;
        const int ff = __ffsll(mm_) - 1;  // -1 when empty
        ids[u] = (lo ? ff : 64 + ff) & 127;                   // in-bounds always
        const unsigned long long cl = mm_ & (mm_ - 1ull);
        bm0 = lo ? cl : bm0;
        bm1 = lo ? bm1 : cl;
    }

    // ---- gather band values: 16 independent sval reads, bank == d for ANY
    // id (addr = id*32+d) -> conflict-free by construction ----
    float ki[NK];
    #pragma unroll
    for (int u = 0; u < CAP; ++u)
        ki[u] = (u < mc_sp) ? sval[ids[u] * DD + d] : INFV;
    const bool t0 = (ne >= 1) && (be0 == selbin) && !fb;
    const bool t1 = (ne == 2) && (be1 == selbin) && !fb;
    ki[CAP]     = t0 ? exv0 : INFV;
    ki[CAP + 1] = t1 ? exv1 : INFV;

    // ---- rank within band: Batcher odd-even sorting network on 18 slots.
    // INF padding sorts high; valid count = mexp > rp (when !fb), so
    // sorted[rp] is exactly the multiset lower median. All indices are
    // compile-time constants after unroll -> ki[] stays in registers. ----
    #pragma unroll
    for (int p = 1; p < NK; p <<= 1) {
        #pragma unroll
        for (int kk = p; kk >= 1; kk >>= 1) {
            #pragma unroll
            for (int j = kk % p; j + kk < NK; j += 2 * kk) {
                #pragma unroll
                for (int i = 0; i < kk; ++i) {
                    const int a = i + j, c = i + j + kk;
                    if (c < NK && (a / (2 * p)) == (c / (2 * p))) {
                        const float lo_ = fminf(ki[a], ki[c]);
                        const float hi_ = fmaxf(ki[a], ki[c]);
                        ki[a] = lo_; ki[c] = hi_;
                    }
                }
            }
        }
    }
    float result = ki[0];
    #pragma unroll
    for (int u = 1; u < NK; ++u) result = (rp == (uint32_t)u) ? ki[u] : result;

    // ---- full fallback (band > CAP; ~1e-5 of lanes): BOUNDED 8-wide-ILP
    // exact scan over all k (serial mask-walks create straggler tails, R13) ----
    if (__ballot(fb)) {
        bool done = !fb;
        for (int i0 = 0; __ballot(!done && i0 < k); i0 += 8) {
            float k8[8]; uint32_t c8[8];
            #pragma unroll
            for (int u = 0; u < 8; ++u) {
                int i = i0 + u;
                float sv = sval[nb[i & 127] * DD + d];
                float ev = ((i - dg) == 0) ? exv0 : exv1;
                float v = (i < dg) ? sv : ev;
                k8[u] = (i < k) ? v : INFV;
                c8[u] = 0;
            }
            for (int j = 0; j < dg; ++j) {
                float xv = sval[nb[j] * DD + d];
                #pragma unroll
                for (int u = 0; u < 8; ++u) c8[u] += (xv < k8[u]);
            }
            if (ne >= 1) {
                #pragma unroll
                for (int u = 0; u < 8; ++u) c8[u] += (exv0 < k8[u]);
            }
            if (ne == 2) {
                #pragma unroll
                for (int u = 0; u < 8; ++u) c8[u] += (exv1 < k8[u]);
            }
            #pragma unroll
            for (int u = 0; u < 8; ++u) {
                if (!done && (i0 + u) < k && c8[u] == r) { result = k8[u]; done = true; }
            }
        }
        if (__ballot(!done)) {  // duplicates across rank: exact multiset selection
            for (int i0 = 0; __ballot(!done && i0 < k); i0 += 4) {
                float k4[4]; uint32_t lt4[4], le4[4];
                #pragma unroll
                for (int u = 0; u < 4; ++u) {
                    int i = i0 + u;
                    float sv = sval[nb[i & 127] * DD + d];
                    float ev = ((i - dg) == 0) ? exv0 : exv1;
                    float v = (i < dg) ? sv : ev;
                    k4[u] = (i < k) ? v : INFV;
                    lt4[u] = 0; le4[u] = 0;
                }
                for (int j = 0; j < dg; ++j) {
                    float xv = sval[nb[j] * DD + d];
                    #pragma unroll
                    for (int u = 0; u < 4; ++u) { lt4[u] += (xv < k4[u]); le4[u] += (xv <= k4[u]); }
                }
                if (ne >= 1) {
                    #pragma unroll
                    for (int u = 0; u < 4; ++u) { lt4[u] += (exv0 < k4[u]); le4[u] += (exv0 <= k4[u]); }
                }
                if (ne == 2) {
                    #pragma unroll
                    for (int u = 0; u < 4; ++u) { lt4[u] += (exv1 < k4[u]); le4[u] += (exv1 <= k4[u]); }
                }
                #pragma unroll
                for (int u = 0; u < 4; ++u) {
                    if (!done && (i0 + u) < k && lt4[u] <= r && r < le4[u]) {
                        result = k4[u]; done = true;
                    }
                }
            }
        }
    }

    out[(((size_t)(b * TT + t) * NN) + n) * DD + d] = result;
}

extern "C" void kernel_launch(void* const* d_in, const int* in_sizes, int n_in,
                              void* d_out, int out_size, void* d_ws, size_t ws_size,
                              hipStream_t stream) {
    const float* xs = (const float*)d_in[0];
    const int* A = (const int*)d_in[1];
    float* out = (float*)d_out;
    (void)d_ws; (void)ws_size;  // no workspace: adjacency fused into the kernel

    median_kernel<<<NBLK, TPB, 0, stream>>>(xs, A, out);
}